// Round 14
// baseline (131.550 us; speedup 1.0000x reference)
//
#include <hip/hip_runtime.h>
#include <math.h>

#define BATCH 8
#define NN 2048
#define FF 128

typedef __attribute__((ext_vector_type(4))) float f32x4;
typedef _Float16 half8 __attribute__((ext_vector_type(8)));

__device__ __forceinline__ unsigned short h2u(_Float16 h) {
    return __builtin_bit_cast(unsigned short, h);
}

// ---------------------------------------------------------------------------
// k_h: h = x@W via fp16-split MFMA (xh*Wh + xl*Wh + xh*Wl) with W fragments
// derived IN-REGISTER from fp32 W. 1024 blocks x 256 thr = 4 blocks/CU;
// block = 16 rows x 128 cols; wave = 16 rows x 32 cols. h stored as one fp16
// plane in B-frag layout; epilogue: factored exponentials Sg/S2g/Eg/E2g.
// Each block also packs 2 adj rows -> transposed bitmask amT[jw][i] (ballot).
// R10 lesson: NO device-scope fences (L2-flush storm, ~300us).
// R11 lesson: NO launch_bounds waves/EU=8 (64-VGPR cap -> accumulator spill).
// ---------------------------------------------------------------------------
__global__ __launch_bounds__(256) void k_h(const float* __restrict__ x,
                                           const int* __restrict__ adj,
                                           const float* __restrict__ W,
                                           const float* __restrict__ a_src,
                                           const float* __restrict__ a_dst,
                                           unsigned short* __restrict__ hF,
                                           float* __restrict__ Eg,  float* __restrict__ E2g,
                                           float* __restrict__ Sg,  float* __restrict__ S2g,
                                           unsigned* __restrict__ amT) {
    __shared__ float sred[4 * 16];
    __shared__ float dred[4 * 16];

    const int t = threadIdx.x;
    const int w = t >> 6, lane = t & 63;
    const int nl = lane & 15, quad = lane >> 4;
    const int row0 = blockIdx.x * 16;
    const int b = row0 >> 11, jloc0 = row0 & 2047;
    const int gr = row0 + nl;
    const int nt0 = w * 2;  // wave's ntiles: nt0, nt0+1

    // ---- adj pack: 2 rows/block; wave -> (row w>>1, seg half w&1) ----
    {
        const int prow = blockIdx.x * 2 + (w >> 1);
        const int* __restrict__ ar = adj + (size_t)prow * NN;
        const int s0 = (w & 1) * 16;
        #pragma unroll
        for (int s = 0; s < 16; ++s) {
            const int seg = s0 + s;
            const unsigned long long m = __ballot(ar[seg * 64 + lane] != 0);
            if (lane == 0)  amT[(size_t)(seg * 2) * NN + prow] = (unsigned)m;
            if (lane == 32) amT[(size_t)(seg * 2 + 1) * NN + prow] = (unsigned)(m >> 32);
        }
    }

    f32x4 acc[2] = {{0.f,0.f,0.f,0.f},{0.f,0.f,0.f,0.f}};

    #pragma unroll
    for (int ks = 0; ks < 4; ++ks) {
        const float4 xa = *reinterpret_cast<const float4*>(&x[(size_t)gr * FF + ks * 32 + quad * 8]);
        const float4 xb = *reinterpret_cast<const float4*>(&x[(size_t)gr * FF + ks * 32 + quad * 8 + 4]);
        const float xv[8] = {xa.x, xa.y, xa.z, xa.w, xb.x, xb.y, xb.z, xb.w};
        half8 ah, al;
        #pragma unroll
        for (int i = 0; i < 8; ++i) {
            const _Float16 hh = (_Float16)xv[i];
            ah[i] = hh;
            al[i] = (_Float16)(xv[i] - (float)hh);
        }
        #pragma unroll
        for (int nn = 0; nn < 2; ++nn) {
            const float* __restrict__ wp = W + (size_t)(ks * 32 + quad * 8) * FF + (nt0 + nn) * 16 + nl;
            half8 bh, bl;
            #pragma unroll
            for (int j = 0; j < 8; ++j) {
                const float wv = wp[j * FF];
                const _Float16 hh = (_Float16)wv;
                bh[j] = hh;
                bl[j] = (_Float16)(wv - (float)hh);
            }
            acc[nn] = __builtin_amdgcn_mfma_f32_16x16x32_f16(ah, bh, acc[nn], 0, 0, 0);
            acc[nn] = __builtin_amdgcn_mfma_f32_16x16x32_f16(al, bh, acc[nn], 0, 0, 0);
            acc[nn] = __builtin_amdgcn_mfma_f32_16x16x32_f16(ah, bl, acc[nn], 0, 0, 0);
        }
    }

    // ---- h store: fp16 plane, B-frag layout [b][nt][jg][n][u] ----
    const int jloc = jloc0 + quad * 4;
    const int jg = jloc >> 3, u0 = jloc & 7;   // u0 in {0,4}
    #pragma unroll
    for (int nn = 0; nn < 2; ++nn) {
        ushort4 hv;
        hv.x = h2u((_Float16)acc[nn][0]);
        hv.y = h2u((_Float16)acc[nn][1]);
        hv.z = h2u((_Float16)acc[nn][2]);
        hv.w = h2u((_Float16)acc[nn][3]);
        *reinterpret_cast<ushort4*>(&hF[(size_t)b * 262144 + (nt0 + nn) * 32768 + jg * 128 + nl * 8 + u0]) = hv;
    }

    // ---- s_src / s_dst partials over this wave's 32 cols ----
    float as[2], ad[2];
    #pragma unroll
    for (int nn = 0; nn < 2; ++nn) {
        const int col = (nt0 + nn) * 16 + nl;
        as[nn] = a_src[col];
        ad[nn] = a_dst[col];
    }
    #pragma unroll
    for (int r = 0; r < 4; ++r) {
        float sp = acc[0][r] * as[0] + acc[1][r] * as[1];
        float dp = acc[0][r] * ad[0] + acc[1][r] * ad[1];
        #pragma unroll
        for (int off = 8; off >= 1; off >>= 1) {
            sp += __shfl_xor(sp, off, 16);
            dp += __shfl_xor(dp, off, 16);
        }
        if (nl == 0) {
            sred[w * 16 + quad * 4 + r] = sp;
            dred[w * 16 + quad * 4 + r] = dp;
        }
    }
    __syncthreads();
    if (t < 16) {
        const float sp = sred[t] + sred[16 + t] + sred[32 + t] + sred[48 + t];
        const float dp = dred[t] + dred[16 + t] + dred[32 + t] + dred[48 + t];
        const int row = row0 + t;
        Sg[row]  = __expf(sp - 2.f);
        S2g[row] = __expf(0.2f * sp - 2.f);
        Eg[row]  = __expf(dp - 2.f);
        E2g[row] = __expf(0.2f * dp - 2.f);
    }
}

// ---------------------------------------------------------------------------
// k_attn DIRECT-WRITE: p = mask ? max(Si*Ej, S2i*E2j) : 0 (= exp(lrelu-4)),
// full j-range per block -> normalized out written directly; k_comb DELETED.
// grid (64, 8) = 512 blocks x 1024 thr (16 waves) = 2 blocks/CU; block =
// 32 rows x 128 cols x 2048 j (32 tiles of 64). Wave = 1 mtile x 1 ntile ->
// acc is ONE f32x4 (4 VGPRs); slim working set aims <=64 VGPR so HW packs
// 32 waves/CU on its own (launch_bounds stays ,4 — R11: never force the cap).
// p-gen: 2 p/thread (1 row x 2 j); l per-thread VALU, width-32 shuffle reduce.
// LDS: 9.2 KB pA double-buffer + 32 floats l_s. 1 barrier/tile.
// ---------------------------------------------------------------------------
__global__ __launch_bounds__(1024, 4) void k_attn(const unsigned short* __restrict__ hF,
                                                  const unsigned* __restrict__ amT,
                                                  const float* __restrict__ Eg,
                                                  const float* __restrict__ E2g,
                                                  const float* __restrict__ Sg,
                                                  const float* __restrict__ S2g,
                                                  float* __restrict__ out) {
    __shared__ unsigned short pA[2 * 32 * 72];   // 9.2 KB
    __shared__ float l_s[32];

    const int t = threadIdx.x;
    const int b = blockIdx.y;
    const int i0 = blockIdx.x * 32;

    // ---- p-gen ids: thread = 1 row x 2 j ----
    const int prow = t >> 5;        // 0..31
    const int jp = t & 31;          // j = jp*2, jp*2+1 within tile
    const float Sa  = Sg[(size_t)b * NN + i0 + prow];
    const float S2a = S2g[(size_t)b * NN + i0 + prow];
    const int pwo = prow * 72 + jp * 2;
    const int bit = (jp & 15) * 2;
    const float* __restrict__ Egb  = Eg  + (size_t)b * NN;
    const float* __restrict__ E2gb = E2g + (size_t)b * NN;
    const unsigned* __restrict__ amb = amT + i0 + prow;

    // ---- MFMA ids: wave = (mt = w&1) mtile x (nt = w>>1) ntile ----
    const int w = t >> 6, lane = t & 63;
    const int nl = lane & 15, quad = lane >> 4;
    const int mt = w & 1, nt = w >> 1;
    const unsigned short* __restrict__ hFb = hF + (size_t)b * 262144;
    const int bofs = nt * 32768 + quad * 128 + nl * 8;
    const int aofs = (mt * 16 + nl) * 72 + quad * 8;

    f32x4 acc = {0.f, 0.f, 0.f, 0.f};
    float la = 0.f;

    for (int tt = 0; tt < 32; ++tt) {
        const int buf = tt & 1;
        const int jofs = tt * 1024;              // 64 j x 16 ushort per j-group

        // B-frags for this wave's single ntile (2 k-halves)
        const half8 b0 = *reinterpret_cast<const half8*>(hFb + bofs + jofs);
        const half8 b1 = *reinterpret_cast<const half8*>(hFb + bofs + jofs + 512);

        // ---- p-gen: 1 row x 2 j (E/mask direct from global, L1-broadcast) ----
        {
            const int jb = tt * 64 + jp * 2;
            const float2 ej  = *reinterpret_cast<const float2*>(&Egb[jb]);
            const float2 e2j = *reinterpret_cast<const float2*>(&E2gb[jb]);
            const unsigned mw = amb[(size_t)(tt * 2 + (jp >> 4)) * NN];
            const float u0 = fmaxf(Sa * ej.x, S2a * e2j.x);
            const float u1 = fmaxf(Sa * ej.y, S2a * e2j.y);
            const float p0 = ((mw >> bit) & 1u) ? u0 : 0.f;
            const float p1 = ((mw >> (bit + 1)) & 1u) ? u1 : 0.f;
            la += p0 + p1;
            const unsigned pk = (unsigned)h2u((_Float16)p0) |
                                ((unsigned)h2u((_Float16)p1) << 16);
            *reinterpret_cast<unsigned*>(&pA[buf * 2304 + pwo]) = pk;
        }

        __syncthreads();

        const half8 a0 = *reinterpret_cast<const half8*>(&pA[buf * 2304 + aofs]);
        const half8 a1 = *reinterpret_cast<const half8*>(&pA[buf * 2304 + aofs + 32]);
        acc = __builtin_amdgcn_mfma_f32_16x16x32_f16(a0, b0, acc, 0, 0, 0);
        acc = __builtin_amdgcn_mfma_f32_16x16x32_f16(a1, b1, acc, 0, 0, 0);
    }

    // ---- l reduction across the 32 jp threads of each row ----
    #pragma unroll
    for (int off = 16; off >= 1; off >>= 1) la += __shfl_xor(la, off, 32);
    if (jp == 0) l_s[prow] = la;
    __syncthreads();

    // ---- epilogue: C/D layout col=lane&15, row=quad*4+reg; normalize ----
    const int col = nt * 16 + nl;
    #pragma unroll
    for (int r = 0; r < 4; ++r) {
        const int lrow = mt * 16 + quad * 4 + r;
        const float l = l_s[lrow];
        const float inv = (l > 0.f) ? 1.f / l : 0.f;
        out[((size_t)b * NN + i0 + lrow) * FF + col] = acc[r] * inv;
    }
}

extern "C" void kernel_launch(void* const* d_in, const int* in_sizes, int n_in,
                              void* d_out, int out_size, void* d_ws, size_t ws_size,
                              hipStream_t stream) {
    const float* x     = (const float*)d_in[0];
    const int*   adj   = (const int*)d_in[1];
    const float* W     = (const float*)d_in[2];
    const float* a_src = (const float*)d_in[3];
    const float* a_dst = (const float*)d_in[4];
    float* out = (float*)d_out;

    unsigned short* hF = (unsigned short*)d_ws;           // 4 MB
    float* Eg  = (float*)(hF + 2097152);                  // 64 KB
    float* E2g = Eg + 16384;                              // 64 KB
    float* Sg  = E2g + 16384;                             // 64 KB
    float* S2g = Sg + 16384;                              // 64 KB
    unsigned* amT = (unsigned*)(S2g + 16384);             // 512 KB

    k_h<<<1024, 256, 0, stream>>>(x, adj, W, a_src, a_dst, hF, Eg, E2g, Sg, S2g, amT);
    k_attn<<<dim3(NN / 32, BATCH), 1024, 0, stream>>>(hF, amT, Eg, E2g, Sg, S2g, out);
}

// Round 15
// 113.382 us; speedup vs baseline: 1.1602x; 1.1602x over previous
//
#include <hip/hip_runtime.h>
#include <math.h>

#define BATCH 8
#define NN 2048
#define FF 128

typedef __attribute__((ext_vector_type(4))) float f32x4;
typedef _Float16 half8 __attribute__((ext_vector_type(8)));

__device__ __forceinline__ unsigned short h2u(_Float16 h) {
    return __builtin_bit_cast(unsigned short, h);
}

// ---------------------------------------------------------------------------
// k_h: h = x@W via fp16-split MFMA (xh*Wh + xl*Wh + xh*Wl) with W fragments
// derived IN-REGISTER from fp32 W (W is L1/L2-resident; no prep kernel).
// 1024 blocks x 256 thr = 4 blocks/CU: block = 16 rows x 128 cols; wave =
// 16 rows x 32 cols (2 ntiles). h stored as one fp16 plane in B-frag layout;
// epilogue: factored exponentials Sg/S2g/Eg/E2g.
// Each block also packs 2 adj rows -> transposed bitmask amT[jw][i] (ballot).
// R10 lesson: NO device-scope fences (L2-flush storm, ~300us).
// R11 lesson: NO launch_bounds waves/EU=8 (64-VGPR cap -> accumulator spill).
// R14 lesson: keep blocks at 8 waves / >=8 MFMA per barrier — 16-wave blocks
// with 2 MFMAs per barrier went barrier-latency-bound (48us, MfmaUtil 6%).
// ---------------------------------------------------------------------------
__global__ __launch_bounds__(256) void k_h(const float* __restrict__ x,
                                           const int* __restrict__ adj,
                                           const float* __restrict__ W,
                                           const float* __restrict__ a_src,
                                           const float* __restrict__ a_dst,
                                           unsigned short* __restrict__ hF,
                                           float* __restrict__ Eg,  float* __restrict__ E2g,
                                           float* __restrict__ Sg,  float* __restrict__ S2g,
                                           unsigned* __restrict__ amT) {
    __shared__ float sred[4 * 16];
    __shared__ float dred[4 * 16];

    const int t = threadIdx.x;
    const int w = t >> 6, lane = t & 63;
    const int nl = lane & 15, quad = lane >> 4;
    const int row0 = blockIdx.x * 16;
    const int b = row0 >> 11, jloc0 = row0 & 2047;
    const int gr = row0 + nl;
    const int nt0 = w * 2;  // wave's ntiles: nt0, nt0+1

    // ---- adj pack: 2 rows/block; wave -> (row w>>1, seg half w&1) ----
    {
        const int prow = blockIdx.x * 2 + (w >> 1);
        const int* __restrict__ ar = adj + (size_t)prow * NN;
        const int s0 = (w & 1) * 16;
        #pragma unroll
        for (int s = 0; s < 16; ++s) {
            const int seg = s0 + s;
            const unsigned long long m = __ballot(ar[seg * 64 + lane] != 0);
            if (lane == 0)  amT[(size_t)(seg * 2) * NN + prow] = (unsigned)m;
            if (lane == 32) amT[(size_t)(seg * 2 + 1) * NN + prow] = (unsigned)(m >> 32);
        }
    }

    f32x4 acc[2] = {{0.f,0.f,0.f,0.f},{0.f,0.f,0.f,0.f}};

    #pragma unroll
    for (int ks = 0; ks < 4; ++ks) {
        const float4 xa = *reinterpret_cast<const float4*>(&x[(size_t)gr * FF + ks * 32 + quad * 8]);
        const float4 xb = *reinterpret_cast<const float4*>(&x[(size_t)gr * FF + ks * 32 + quad * 8 + 4]);
        const float xv[8] = {xa.x, xa.y, xa.z, xa.w, xb.x, xb.y, xb.z, xb.w};
        half8 ah, al;
        #pragma unroll
        for (int i = 0; i < 8; ++i) {
            const _Float16 hh = (_Float16)xv[i];
            ah[i] = hh;
            al[i] = (_Float16)(xv[i] - (float)hh);
        }
        #pragma unroll
        for (int nn = 0; nn < 2; ++nn) {
            const float* __restrict__ wp = W + (size_t)(ks * 32 + quad * 8) * FF + (nt0 + nn) * 16 + nl;
            half8 bh, bl;
            #pragma unroll
            for (int j = 0; j < 8; ++j) {
                const float wv = wp[j * FF];
                const _Float16 hh = (_Float16)wv;
                bh[j] = hh;
                bl[j] = (_Float16)(wv - (float)hh);
            }
            acc[nn] = __builtin_amdgcn_mfma_f32_16x16x32_f16(ah, bh, acc[nn], 0, 0, 0);
            acc[nn] = __builtin_amdgcn_mfma_f32_16x16x32_f16(al, bh, acc[nn], 0, 0, 0);
            acc[nn] = __builtin_amdgcn_mfma_f32_16x16x32_f16(ah, bl, acc[nn], 0, 0, 0);
        }
    }

    // ---- h store: fp16 plane, B-frag layout [b][nt][jg][n][u] ----
    const int jloc = jloc0 + quad * 4;
    const int jg = jloc >> 3, u0 = jloc & 7;   // u0 in {0,4}
    #pragma unroll
    for (int nn = 0; nn < 2; ++nn) {
        ushort4 hv;
        hv.x = h2u((_Float16)acc[nn][0]);
        hv.y = h2u((_Float16)acc[nn][1]);
        hv.z = h2u((_Float16)acc[nn][2]);
        hv.w = h2u((_Float16)acc[nn][3]);
        *reinterpret_cast<ushort4*>(&hF[(size_t)b * 262144 + (nt0 + nn) * 32768 + jg * 128 + nl * 8 + u0]) = hv;
    }

    // ---- s_src / s_dst partials over this wave's 32 cols ----
    float as[2], ad[2];
    #pragma unroll
    for (int nn = 0; nn < 2; ++nn) {
        const int col = (nt0 + nn) * 16 + nl;
        as[nn] = a_src[col];
        ad[nn] = a_dst[col];
    }
    #pragma unroll
    for (int r = 0; r < 4; ++r) {
        float sp = acc[0][r] * as[0] + acc[1][r] * as[1];
        float dp = acc[0][r] * ad[0] + acc[1][r] * ad[1];
        #pragma unroll
        for (int off = 8; off >= 1; off >>= 1) {
            sp += __shfl_xor(sp, off, 16);
            dp += __shfl_xor(dp, off, 16);
        }
        if (nl == 0) {
            sred[w * 16 + quad * 4 + r] = sp;
            dred[w * 16 + quad * 4 + r] = dp;
        }
    }
    __syncthreads();
    if (t < 16) {
        const float sp = sred[t] + sred[16 + t] + sred[32 + t] + sred[48 + t];
        const float dp = dred[t] + dred[16 + t] + dred[32 + t] + dred[48 + t];
        const int row = row0 + t;
        Sg[row]  = __expf(sp - 2.f);
        S2g[row] = __expf(0.2f * sp - 2.f);
        Eg[row]  = __expf(dp - 2.f);
        E2g[row] = __expf(0.2f * dp - 2.f);
    }
}

// ---------------------------------------------------------------------------
// k_attn: p = mask ? max(Si*Ej, S2i*E2j) : 0  (= exp(lrelu(si+sj) - 4)).
// grid (32, 8, 2): 512 blocks x 512 thr (8 waves). LDS = pA only (18 KB);
// E/E2/mask read direct from global (L1-broadcast). 16 j-tiles of 64; one
// barrier per tile with 8 MFMAs/wave between barriers (R14: don't go finer).
// l accumulated per-thread in VALU, one end shuffle reduction. Writes
// UNNORMALIZED P/L partials; k_comb merges (kernel boundary = device sync).
// ---------------------------------------------------------------------------
__global__ __launch_bounds__(512, 4) void k_attn(const unsigned short* __restrict__ hF,
                                                 const unsigned* __restrict__ amT,
                                                 const float* __restrict__ Eg,
                                                 const float* __restrict__ E2g,
                                                 const float* __restrict__ Sg,
                                                 const float* __restrict__ S2g,
                                                 float* __restrict__ P,
                                                 float* __restrict__ L) {
    __shared__ unsigned short pA[2 * 64 * 72];   // 18 KB

    const int t = threadIdx.x;
    const int b = blockIdx.y;
    const int i0 = blockIdx.x * 64;
    const int jh = blockIdx.z;                   // 0..1
    const int jbase = jh * 1024;

    // ---- p-gen ids: thread = rows {2rp, 2rp+1} x 4 j ----
    const int rp = t >> 4, jw4 = t & 15;
    const int ra = rp * 2, rb = ra + 1;
    const float Sa  = Sg[(size_t)b * NN + i0 + ra];
    const float S2a = S2g[(size_t)b * NN + i0 + ra];
    const float Sb  = Sg[(size_t)b * NN + i0 + rb];
    const float S2b = S2g[(size_t)b * NN + i0 + rb];
    const int bitb = (jw4 & 7) * 4;
    const int pwo = ra * 72 + jw4 * 4;
    const float* __restrict__ Egb  = Eg  + (size_t)b * NN + jbase;
    const float* __restrict__ E2gb = E2g + (size_t)b * NN + jbase;
    const unsigned* __restrict__ amb = amT + (size_t)(jh * 32) * NN + i0;

    // ---- MFMA ids: wave = mtiles {mtp, mtp+2} x ntiles {ntp, ntp+4} ----
    const int w = t >> 6, lane = t & 63;
    const int nl = lane & 15, quad = lane >> 4;
    const int mtp = w & 1, ntp = w >> 1;
    const unsigned short* __restrict__ hFb = hF + (size_t)b * 262144;
    int bofs[2], aofs[2];
    #pragma unroll
    for (int nn = 0; nn < 2; ++nn) bofs[nn] = (ntp + nn * 4) * 32768 + (jbase + quad * 8) * 16 + nl * 8;
    #pragma unroll
    for (int mm = 0; mm < 2; ++mm) aofs[mm] = ((mtp + mm * 2) * 16 + nl) * 72 + quad * 8;

    f32x4 acc[2][2] = {{{0.f,0.f,0.f,0.f},{0.f,0.f,0.f,0.f}},{{0.f,0.f,0.f,0.f},{0.f,0.f,0.f,0.f}}};
    float la = 0.f, lb = 0.f;

    for (int tt = 0; tt < 16; ++tt) {
        const int buf = tt & 1;
        const int jofs = tt * 1024;              // 64 j x 16 ushort per j-group

        half8 bfr[2][2];
        #pragma unroll
        for (int nn = 0; nn < 2; ++nn) {
            bfr[nn][0] = *reinterpret_cast<const half8*>(hFb + bofs[nn] + jofs);
            bfr[nn][1] = *reinterpret_cast<const half8*>(hFb + bofs[nn] + jofs + 512);
        }

        // ---- p-gen: 2 rows x 4 j (E/E2/mask direct from global) ----
        {
            const int jb = tt * 64 + jw4 * 4;    // local j in this half
            const float4 ej4  = *reinterpret_cast<const float4*>(&Egb[jb]);
            const float4 e2j4 = *reinterpret_cast<const float4*>(&E2gb[jb]);
            const uint2 mw = *reinterpret_cast<const uint2*>(&amb[(size_t)(tt * 2 + (jw4 >> 3)) * NN + ra]);
            const float ejA[4]  = {ej4.x, ej4.y, ej4.z, ej4.w};
            const float e2jA[4] = {e2j4.x, e2j4.y, e2j4.z, e2j4.w};
            ushort4 ha, hb;
            #pragma unroll
            for (int jj = 0; jj < 4; ++jj) {
                const float ua = fmaxf(Sa * ejA[jj], S2a * e2jA[jj]);
                const float ub = fmaxf(Sb * ejA[jj], S2b * e2jA[jj]);
                const float pa = ((mw.x >> (bitb + jj)) & 1u) ? ua : 0.f;
                const float pb = ((mw.y >> (bitb + jj)) & 1u) ? ub : 0.f;
                la += pa;
                lb += pb;
                ((unsigned short*)&ha)[jj] = h2u((_Float16)pa);
                ((unsigned short*)&hb)[jj] = h2u((_Float16)pb);
            }
            *reinterpret_cast<ushort4*>(&pA[buf * 4608 + pwo]) = ha;
            *reinterpret_cast<ushort4*>(&pA[buf * 4608 + pwo + 72]) = hb;
        }

        __syncthreads();

        half8 afr[2][2];
        #pragma unroll
        for (int mm = 0; mm < 2; ++mm) {
            afr[mm][0] = *reinterpret_cast<const half8*>(&pA[buf * 4608 + aofs[mm]]);
            afr[mm][1] = *reinterpret_cast<const half8*>(&pA[buf * 4608 + aofs[mm] + 32]);
        }
        #pragma unroll
        for (int mm = 0; mm < 2; ++mm) {
            #pragma unroll
            for (int kh = 0; kh < 2; ++kh) {
                acc[mm][0] = __builtin_amdgcn_mfma_f32_16x16x32_f16(afr[mm][kh], bfr[0][kh], acc[mm][0], 0, 0, 0);
                acc[mm][1] = __builtin_amdgcn_mfma_f32_16x16x32_f16(afr[mm][kh], bfr[1][kh], acc[mm][1], 0, 0, 0);
            }
        }
    }

    // ---- l reduction over the 16 jw4 threads of each row pair ----
    #pragma unroll
    for (int off = 8; off >= 1; off >>= 1) {
        la += __shfl_xor(la, off, 16);
        lb += __shfl_xor(lb, off, 16);
    }

    // ---- write this block's unnormalized partial ----
    float* __restrict__ Pb = P + ((size_t)jh * BATCH + b) * 262144;
    float* __restrict__ Lb = L + ((size_t)jh * BATCH + b) * 2048;
    if (jw4 == 0) {
        Lb[i0 + ra] = la;
        Lb[i0 + rb] = lb;
    }
    #pragma unroll
    for (int mm = 0; mm < 2; ++mm) {
        const int lrow = (mtp + mm * 2) * 16 + quad * 4;
        #pragma unroll
        for (int r = 0; r < 4; ++r) {
            #pragma unroll
            for (int nn = 0; nn < 2; ++nn) {
                const int col = (ntp + nn * 4) * 16 + nl;
                Pb[(size_t)(i0 + lrow + r) * FF + col] = acc[mm][nn][r];
            }
        }
    }
}

// ---------------------------------------------------------------------------
// k_comb: out = (P0 + P1) / (L0 + L1); rows with no neighbors -> 0.
// 1024 blocks x 256 thr; thread = 2 float4. All inputs L3-resident.
// ---------------------------------------------------------------------------
__global__ __launch_bounds__(256) void k_comb(const float* __restrict__ P,
                                              const float* __restrict__ L,
                                              float* __restrict__ out) {
    const int g0 = blockIdx.x * 512 + threadIdx.x;
    #pragma unroll
    for (int it = 0; it < 2; ++it) {
        const int g = g0 + it * 256;             // float4 index, 0..524287
        const size_t flat = (size_t)g * 4;
        const int row = (int)(flat >> 7);        // 0..16383 (b*2048 + n)
        const float l = L[row] + L[16384 + row];
        const float inv = (l > 0.f) ? 1.f / l : 0.f;
        const float4 p0 = *reinterpret_cast<const float4*>(&P[flat]);
        const float4 p1 = *reinterpret_cast<const float4*>(&P[2097152 + flat]);
        *reinterpret_cast<float4*>(&out[flat]) =
            make_float4((p0.x + p1.x) * inv, (p0.y + p1.y) * inv,
                        (p0.z + p1.z) * inv, (p0.w + p1.w) * inv);
    }
}

extern "C" void kernel_launch(void* const* d_in, const int* in_sizes, int n_in,
                              void* d_out, int out_size, void* d_ws, size_t ws_size,
                              hipStream_t stream) {
    const float* x     = (const float*)d_in[0];
    const int*   adj   = (const int*)d_in[1];
    const float* W     = (const float*)d_in[2];
    const float* a_src = (const float*)d_in[3];
    const float* a_dst = (const float*)d_in[4];
    float* out = (float*)d_out;

    unsigned short* hF = (unsigned short*)d_ws;           // 4 MB
    float* Eg  = (float*)(hF + 2097152);                  // 64 KB
    float* E2g = Eg + 16384;                              // 64 KB
    float* Sg  = E2g + 16384;                             // 64 KB
    float* S2g = Sg + 16384;                              // 64 KB
    unsigned* amT = (unsigned*)(S2g + 16384);             // 512 KB
    float* P = (float*)(amT + 131072);                    // 16 MB  [2][8][2048][128]
    float* L = P + 4194304;                               // 128 KB [2][8][2048]

    k_h<<<1024, 256, 0, stream>>>(x, adj, W, a_src, a_dst, hF, Eg, E2g, Sg, S2g, amT);
    k_attn<<<dim3(32, BATCH, 2), 512, 0, stream>>>(hF, amT, Eg, E2g, Sg, S2g, P, L);
    k_comb<<<1024, 256, 0, stream>>>(P, L, out);
}